// Round 8
// baseline (183.241 us; speedup 1.0000x reference)
//
#include <hip/hip_runtime.h>
#include <hip/hip_bf16.h>

typedef __hip_bfloat16 bf16;
typedef unsigned short ushort;
typedef __attribute__((ext_vector_type(8))) short short8v;   // bf16x8 MFMA frag
typedef __attribute__((ext_vector_type(4))) float float4v;   // fp32x4 MFMA acc

__device__ __forceinline__ float us2f(unsigned int u) {
    union { unsigned int i; float f; } c; c.i = u << 16; return c.f;
}
__device__ __forceinline__ bf16 f2bf(float x) { return __float2bfloat16(x); }
__device__ __forceinline__ ushort f2bfu(float x) {
    union { float f; unsigned int i; } c; c.f = x;
    unsigned int lsb = (c.i >> 16) & 1;
    return (ushort)((c.i + 0x7FFF + lsb) >> 16);
}
__device__ __forceinline__ float fcf(float x) {               // out f32, clamp NaN
    return fminf(1000.f, fmaxf(-1000.f, x));
}
__device__ __forceinline__ int iclamp(int v, int lo, int hi) {
    return v < lo ? lo : (v > hi ? hi : v);
}

// B=16, S=512, H=1024, K=32 slots, E=1024, L=2
// inputs f32; po int32-or-int64 (detected); out f32: cls[32] | node[1024] | edge[32768]
__device__ __forceinline__ int po_ps(const int* po) {
    return ((po[1] | po[3] | po[5]) == 0) ? 2 : 1;
}
__device__ __forceinline__ int count_n(const int* po, int b, int ps) {
    int n = 0;
    #pragma unroll
    for (int j = 1; j < 32; ++j) n += (po[(b * 32 + j) * ps] > 0) ? 1 : 0;
    return iclamp(n, 0, 31);
}

__global__ __launch_bounds__(256) void k_sentinel(float* __restrict__ out, int nv, float val) {
    int i = blockIdx.x * 256 + threadIdx.x;
    if (i < nv) out[i] = val;
}

// ================= device phase functions =================

// prep: Wct[z][n][k] = combined, transposed, bf16. z=0: ndW^T; z=1: (W1+W3)^T; z=2: (W2-W3)^T
__device__ __forceinline__ void dev_prep(int kt, int nt, int z, int tid,
                                         const float* __restrict__ ndW,
                                         const float* __restrict__ eW,
                                         ushort* __restrict__ Wct, float* smemf)
{
    float (*T)[33] = (float (*)[33])smemf;          // 32x33 = 1056 floats

    const int k_loc = tid >> 3, n0 = (tid & 7) * 4;
    const size_t gofs = (size_t)(kt * 32 + k_loc) * 1024 + nt * 32 + n0;
    float4 v;
    if (z == 0) {
        v = *(const float4*)(ndW + gofs);
    } else if (z == 1) {
        float4 a = *(const float4*)(eW + gofs);
        float4 b = *(const float4*)(eW + (size_t)2048 * 1024 + gofs);
        v = make_float4(a.x + b.x, a.y + b.y, a.z + b.z, a.w + b.w);
    } else {
        float4 a = *(const float4*)(eW + (size_t)1024 * 1024 + gofs);
        float4 b = *(const float4*)(eW + (size_t)2048 * 1024 + gofs);
        v = make_float4(a.x - b.x, a.y - b.y, a.z - b.z, a.w - b.w);
    }
    T[k_loc][n0 + 0] = v.x; T[k_loc][n0 + 1] = v.y;
    T[k_loc][n0 + 2] = v.z; T[k_loc][n0 + 3] = v.w;
    __syncthreads();

    const int n_loc = tid >> 3, k0 = (tid & 7) * 4;
    ushort* dst = Wct + (size_t)z * 1024 * 1024 + (size_t)(nt * 32 + n_loc) * 1024 + kt * 32 + k0;
    ushort4 o;
    o.x = f2bfu(T[k0 + 0][n_loc]); o.y = f2bfu(T[k0 + 1][n_loc]);
    o.z = f2bfu(T[k0 + 2][n_loc]); o.w = f2bfu(T[k0 + 3][n_loc]);
    *(ushort4*)dst = o;
}

// nodes: segment means -> fn rows k != n  (row n is written by cls/naf)
// unroll-by-2 with independent accumulators: 2 loads in flight per thread
__device__ __forceinline__ void dev_nodes(int bx, int tid,
                                          const float* __restrict__ seq,
                                          const int* __restrict__ po,
                                          bf16* __restrict__ fn, int bbase)
{
    const int b_loc = bx >> 5;
    const int k = bx & 31;
    const int b = bbase + b_loc;
    const int ps = po_ps(po);
    const int n = count_n(po, b, ps);
    if (k == n) return;                               // naf row: cls phase writes it

    const int h0 = tid * 4;
    float4 acc = make_float4(0.f, 0.f, 0.f, 0.f);
    if (k < n) {
        int s_end   = iclamp(po[(b * 32 + k + 1) * ps], 1, 511);
        int s_begin = (k == 0) ? 1 : iclamp(po[(b * 32 + k) * ps] + 1, 1, 511);
        if (s_end < s_begin) s_end = s_begin;
        const float inv = 1.0f / (float)(s_end - s_begin + 1);
        float4 acc2 = make_float4(0.f, 0.f, 0.f, 0.f);
        int s = s_begin;
        const float* base = seq + (size_t)b * 524288 + h0;
        for (; s + 1 <= s_end; s += 2) {
            float4 u = *(const float4*)(base + (size_t)s * 1024);
            float4 v = *(const float4*)(base + (size_t)(s + 1) * 1024);
            acc.x += u.x;  acc.y += u.y;  acc.z += u.z;  acc.w += u.w;
            acc2.x += v.x; acc2.y += v.y; acc2.z += v.z; acc2.w += v.w;
        }
        if (s <= s_end) {
            float4 u = *(const float4*)(base + (size_t)s * 1024);
            acc.x += u.x; acc.y += u.y; acc.z += u.z; acc.w += u.w;
        }
        acc.x = (acc.x + acc2.x) * inv; acc.y = (acc.y + acc2.y) * inv;
        acc.z = (acc.z + acc2.z) * inv; acc.w = (acc.w + acc2.w) * inv;
    }
    bf16* dst = fn + (size_t)(b_loc * 32 + k) * 1024 + h0;
    dst[0] = f2bf(acc.x); dst[1] = f2bf(acc.y); dst[2] = f2bf(acc.z); dst[3] = f2bf(acc.w);
}

// cls: cls head partials (no atomics) + naf row of fn.
// thread (c16,kq) owns 4 cols (float4 W loads) x K-chunk of 64; unroll 4.
__device__ __forceinline__ void dev_cls(int b_loc, int q, int tid,
                                        const float* __restrict__ seq,
                                        const int* __restrict__ po,
                                        const float* __restrict__ nafW, const float* __restrict__ nafb,
                                        const float* __restrict__ clsW, const float* __restrict__ clsb,
                                        const float* __restrict__ clsoW,
                                        bf16* __restrict__ fn,
                                        float* __restrict__ cacc,      // [16][16][2] partials
                                        int bbase, float* smemf)
{
    const int b = bbase + b_loc;
    float* xs   = smemf;                              // 1024 floats
    float* redc = smemf + 1024;                       // 16 kq x 64 cols
    float* redn = smemf + 2048;                       // 16 kq x 64 cols
    for (int j = tid; j < 1024; j += 256) xs[j] = seq[(size_t)b * 524288 + j];
    __syncthreads();

    const int c16 = tid & 15, kq = tid >> 4;          // 16 col-groups x 16 K-chunks
    const int col0 = q * 64 + c16 * 4;
    const int kb = kq * 64;
    const float* wc_base = clsW + (size_t)kb * 1024 + col0;
    const float* wn_base = nafW + (size_t)kb * 1024 + col0;
    float4 ac = make_float4(0.f, 0.f, 0.f, 0.f);
    float4 an = make_float4(0.f, 0.f, 0.f, 0.f);
    #pragma unroll 4
    for (int i = 0; i < 64; ++i) {
        const float x = xs[kb + i];
        float4 wc = *(const float4*)(wc_base + (size_t)i * 1024);
        float4 wn = *(const float4*)(wn_base + (size_t)i * 1024);
        ac.x = fmaf(x, wc.x, ac.x); ac.y = fmaf(x, wc.y, ac.y);
        ac.z = fmaf(x, wc.z, ac.z); ac.w = fmaf(x, wc.w, ac.w);
        an.x = fmaf(x, wn.x, an.x); an.y = fmaf(x, wn.y, an.y);
        an.z = fmaf(x, wn.z, an.z); an.w = fmaf(x, wn.w, an.w);
    }
    *(float4*)&redc[kq * 64 + c16 * 4] = ac;
    *(float4*)&redn[kq * 64 + c16 * 4] = an;
    __syncthreads();

    if (tid < 64) {
        const int cl = tid;
        float cs = 0.f, ns = 0.f;
        #pragma unroll
        for (int kk = 0; kk < 16; ++kk) {
            cs += redc[kk * 64 + cl];
            ns += redn[kk * 64 + cl];
        }
        const int hout = q * 64 + cl;
        const int ps = po_ps(po);
        const int n = count_n(po, b, ps);
        fn[(size_t)(b_loc * 32 + n) * 1024 + hout] = f2bf(ns + nafb[hout]);
        float h = tanhf(cs + clsb[hout]);
        float2 ow = ((const float2*)clsoW)[hout];
        float q0 = h * ow.x, q1 = h * ow.y;
        #pragma unroll
        for (int off = 32; off > 0; off >>= 1) {
            q0 += __shfl_down(q0, off, 64);
            q1 += __shfl_down(q1, off, 64);
        }
        if (cl == 0) {
            cacc[(b_loc * 16 + q) * 2 + 0] = q0;
            cacc[(b_loc * 16 + q) * 2 + 1] = q1;
        }
    }
}

// econ: invalid-edge constant (bit-identical to k_edge's invalid-wave computation)
__device__ __forceinline__ void dev_econ(int tid,
                                         const float* __restrict__ edb,
                                         const float* __restrict__ eoW,
                                         float* __restrict__ econ)
{
    if (tid >= 64) return;
    const int lane = tid;
    float a0 = 0.f, a1 = 0.f;
    #pragma unroll
    for (int c = 0; c < 16; ++c) {
        const int idx = c * 64 + lane;
        float t = tanhf(edb[idx]);
        float2 ow = ((const float2*)eoW)[idx];
        a0 = fmaf(t, ow.x, a0);
        a1 = fmaf(t, ow.y, a1);
    }
    #pragma unroll
    for (int off = 32; off > 0; off >>= 1) {
        a0 += __shfl_down(a0, off, 64);
        a1 += __shfl_down(a1, off, 64);
    }
    if (lane == 0) { econ[0] = a0; econ[1] = a1; }
}

// ================= fused A: cls(256) | nodes(512) | prep(3072) | econ(1) =================
// Latency-bound phases (cls, nodes) dispatched first; high-TLP prep fills the machine behind.
__global__ __launch_bounds__(256) void k_fusedA(const float* __restrict__ seq,
                                                const int* __restrict__ po,
                                                const float* __restrict__ nafW, const float* __restrict__ nafb,
                                                const float* __restrict__ clsW, const float* __restrict__ clsb,
                                                const float* __restrict__ clsoW,
                                                const float* __restrict__ ndW,
                                                const float* __restrict__ eW,
                                                const float* __restrict__ edb,
                                                const float* __restrict__ eoW,
                                                bf16* __restrict__ fn,
                                                float* __restrict__ cacc,
                                                ushort* __restrict__ Wct,
                                                float* __restrict__ econ)
{
    __shared__ __align__(16) float smem[3072];
    const int blk = blockIdx.x;
    const int tid = threadIdx.x;
    if (blk < 256) {
        dev_cls(blk & 15, blk >> 4, tid, seq, po, nafW, nafb, clsW, clsb, clsoW, fn, cacc, 0, smem);
    } else if (blk < 768) {
        dev_nodes(blk - 256, tid, seq, po, fn, 0);
    } else if (blk < 3840) {
        const int rem = blk - 768;
        const int z = rem >> 10, t10 = rem & 1023;
        dev_prep(t10 & 31, t10 >> 5, z, tid, ndW, eW, Wct, smem);
    } else {
        dev_econ(tid, edb, eoW, econ);
    }
}

// standalone wrappers (fallback paths)
__global__ __launch_bounds__(256) void k_nodes(const float* __restrict__ seq,
                                               const int* __restrict__ po,
                                               bf16* __restrict__ fn, int bbase)
{
    dev_nodes(blockIdx.x, threadIdx.x, seq, po, fn, bbase);
}
__global__ __launch_bounds__(256) void k_cls(const float* __restrict__ seq,
                                             const int* __restrict__ po,
                                             const float* __restrict__ nafW, const float* __restrict__ nafb,
                                             const float* __restrict__ clsW, const float* __restrict__ clsb,
                                             const float* __restrict__ clsoW,
                                             bf16* __restrict__ fn,
                                             float* __restrict__ cacc, int bbase)
{
    __shared__ __align__(16) float smem[3072];
    dev_cls(blockIdx.x, blockIdx.y, threadIdx.x, seq, po, nafW, nafb, clsW, clsb, clsoW, fn, cacc, bbase, smem);
}

// ---------------- k_huv_mfma: fn(16 rows) @ Wct[z] via 16x16x32 bf16 MFMA ----------------
// 1-D grid 768 with XCD-aware chunking: t = (bid&7)*96 + (bid>>3) gives each XCD 96
// contiguous tasks = 3 complete (cc,z) slice-groups -> each per-XCD L2 fetches 3 B-slices
// (768 KB, L2-resident) instead of up to 24; ~8x less L3->L2 traffic on Wct.
// Decode: z = t>>8, cc = (t>>5)&7, rt = t&31 (contiguous t share (cc,z)).
// z==0 writes per-(row,cc) partials into nacc[512][8][2] (no atomics).
__global__ __launch_bounds__(256) void k_huv_mfma(const bf16* __restrict__ X,
                                                  const ushort* __restrict__ Wct,
                                                  const float* __restrict__ ndb,
                                                  const float* __restrict__ noW,
                                                  float* __restrict__ nacc,
                                                  bf16* __restrict__ U,
                                                  bf16* __restrict__ V)
{
    int t = blockIdx.x;
    t = (t & 7) * 96 + (t >> 3);          // bijective: 768 = 8 XCDs x 96 chunk
    const int z  = t >> 8;
    const int cc = (t >> 5) & 7;
    const int rt = t & 31;
    const int tid = threadIdx.x;
    const int w = tid >> 6, lane = tid & 63;
    const int quad = lane >> 4, l16 = lane & 15;
    const int rbase = rt * 16;

    __shared__ char smem[32768];
    short* A_lds = (short*)smem;          // frag-order A: slot((ks>>5), quad, m) * 8 bf16
    float* Rs    = (float*)smem;          // 16 x 128 f32 epilogue buffer (aliases A)

    // stage A (16 rows x 1024 K) in MFMA fragment order
    {
        const int r = tid >> 4, s = tid & 15;
        const ushort* src = (const ushort*)X + (size_t)(rbase + r) * 1024 + s * 64;
        #pragma unroll
        for (int cch = 0; cch < 8; ++cch) {
            const int k0 = s * 64 + cch * 8;
            uint4 v = *(const uint4*)(src + cch * 8);
            const int slot = ((k0 >> 5) * 64 + ((k0 >> 3) & 3) * 16 + r) * 8;
            *(uint4*)&A_lds[slot] = v;
        }
    }
    __syncthreads();

    const ushort* Wz = Wct + (size_t)z * 1024 * 1024;
    const int nbase = cc * 128 + w * 32;
    const ushort* B0 = Wz + (size_t)(nbase + l16) * 1024 + quad * 8;
    const ushort* B1 = B0 + (size_t)16 * 1024;

    float4v acc0 = {0.f, 0.f, 0.f, 0.f};
    float4v acc1 = {0.f, 0.f, 0.f, 0.f};

    #pragma unroll 4
    for (int ks = 0; ks < 1024; ks += 32) {
        short8v a  = *(const short8v*)&A_lds[((ks >> 5) * 64 + quad * 16 + l16) * 8];
        short8v b0 = *(const short8v*)(B0 + ks);
        short8v b1 = *(const short8v*)(B1 + ks);
        acc0 = __builtin_amdgcn_mfma_f32_16x16x32_bf16(a, b0, acc0, 0, 0, 0);
        acc1 = __builtin_amdgcn_mfma_f32_16x16x32_bf16(a, b1, acc1, 0, 0, 0);
    }
    __syncthreads();                      // A dead; reuse as Rs

    // C/D layout: row = quad*4 + reg, col = l16 (verified m89)
    #pragma unroll
    for (int reg = 0; reg < 4; ++reg) {
        Rs[(quad * 4 + reg) * 128 + w * 32 + l16]      = acc0[reg];
        Rs[(quad * 4 + reg) * 128 + w * 32 + 16 + l16] = acc1[reg];
    }
    __syncthreads();

    const int row = tid >> 4;
    const int c0 = (tid & 15) * 8;
    const int gcol0 = cc * 128 + c0;
    const float* src = &Rs[row * 128 + c0];
    float s[8];
    {
        float4 a = ((const float4*)src)[0];
        float4 b = ((const float4*)src)[1];
        s[0] = a.x; s[1] = a.y; s[2] = a.z; s[3] = a.w;
        s[4] = b.x; s[5] = b.y; s[6] = b.z; s[7] = b.w;
    }
    if (z == 0) {
        float q0 = 0.f, q1 = 0.f;
        #pragma unroll
        for (int e = 0; e < 8; ++e) {
            float t2 = tanhf(s[e] + ndb[gcol0 + e]);
            float2 ow = ((const float2*)noW)[gcol0 + e];
            q0 = fmaf(t2, ow.x, q0);
            q1 = fmaf(t2, ow.y, q1);
        }
        #pragma unroll
        for (int off = 8; off > 0; off >>= 1) {
            q0 += __shfl_down(q0, off, 16);
            q1 += __shfl_down(q1, off, 16);
        }
        if ((tid & 15) == 0) {
            float* np = nacc + ((size_t)(rbase + row) * 8 + cc) * 2;
            np[0] = q0; np[1] = q1;
        }
    } else {
        bf16* dstbuf = (z == 1) ? U : V;
        bf16* dst = dstbuf + (size_t)(rbase + row) * 1024 + gcol0;
        #pragma unroll
        for (int e = 0; e < 8; ++e) dst[e] = f2bf(s[e]);
    }
}

// ---------------- k_huv_valu: fallback (ws too small for Wct) ----------------
__global__ __launch_bounds__(256) void k_huv_valu(const bf16* __restrict__ X,
                                                  const float* __restrict__ ndW, const float* __restrict__ ndb,
                                                  const float* __restrict__ noW,
                                                  const float* __restrict__ eW,
                                                  float* __restrict__ nacc,
                                                  bf16* __restrict__ U,
                                                  bf16* __restrict__ V)
{
    const int rt = blockIdx.x, cc = blockIdx.y, z = blockIdx.z;
    const int tid = threadIdx.x;
    const int w = tid >> 6, lane = tid & 63;
    const int rg = lane >> 4, cg = lane & 15;
    const int rbase = rt * 16;
    const int colb = cc * 128 + cg * 8;

    __shared__ float LDSb[8192];
    float* Xs = LDSb;
    float* Rs = LDSb;

    const float* W0;
    const float* W1 = nullptr;
    float sgn = 1.f;
    if (z == 0)      { W0 = ndW; }
    else if (z == 1) { W0 = eW; W1 = eW + (size_t)2048 * 1024; }
    else             { W0 = eW + (size_t)1024 * 1024; W1 = eW + (size_t)2048 * 1024; sgn = -1.f; }

    float acc[32];
    #pragma unroll
    for (int i = 0; i < 32; ++i) acc[i] = 0.f;

    const int sr = tid & 15, sq0 = tid >> 4;
    const ushort* Xu = (const ushort*)X;

    for (int ks = 0; ks < 1024; ks += 256) {
        __syncthreads();
        #pragma unroll
        for (int it = 0; it < 4; ++it) {
            int qq = sq0 + it * 16;
            ushort4 xv = *(const ushort4*)(Xu + (size_t)(rbase + sr) * 1024 + ks + qq * 4);
            int kk = qq * 4;
            Xs[(kk + 0) * 16 + sr] = us2f(xv.x);
            Xs[(kk + 1) * 16 + sr] = us2f(xv.y);
            Xs[(kk + 2) * 16 + sr] = us2f(xv.z);
            Xs[(kk + 3) * 16 + sr] = us2f(xv.w);
        }
        __syncthreads();
        const int k0 = ks + w * 64;
        for (int kk = 0; kk < 64; ++kk) {
            float4 xv = *(const float4*)&Xs[(w * 64 + kk) * 16 + rg * 4];
            const float* wp0 = W0 + (size_t)(k0 + kk) * 1024 + colb;
            float4 wa = ((const float4*)wp0)[0];
            float4 wb = ((const float4*)wp0)[1];
            if (W1) {
                const float* wp1 = W1 + (size_t)(k0 + kk) * 1024 + colb;
                float4 va = ((const float4*)wp1)[0];
                float4 vb = ((const float4*)wp1)[1];
                wa.x = fmaf(sgn, va.x, wa.x); wa.y = fmaf(sgn, va.y, wa.y);
                wa.z = fmaf(sgn, va.z, wa.z); wa.w = fmaf(sgn, va.w, wa.w);
                wb.x = fmaf(sgn, vb.x, wb.x); wb.y = fmaf(sgn, vb.y, wb.y);
                wb.z = fmaf(sgn, vb.z, wb.z); wb.w = fmaf(sgn, vb.w, wb.w);
            }
            float xr[4] = {xv.x, xv.y, xv.z, xv.w};
            #pragma unroll
            for (int rr = 0; rr < 4; ++rr) {
                acc[rr*8+0] = fmaf(xr[rr], wa.x, acc[rr*8+0]);
                acc[rr*8+1] = fmaf(xr[rr], wa.y, acc[rr*8+1]);
                acc[rr*8+2] = fmaf(xr[rr], wa.z, acc[rr*8+2]);
                acc[rr*8+3] = fmaf(xr[rr], wa.w, acc[rr*8+3]);
                acc[rr*8+4] = fmaf(xr[rr], wb.x, acc[rr*8+4]);
                acc[rr*8+5] = fmaf(xr[rr], wb.y, acc[rr*8+5]);
                acc[rr*8+6] = fmaf(xr[rr], wb.z, acc[rr*8+6]);
                acc[rr*8+7] = fmaf(xr[rr], wb.w, acc[rr*8+7]);
            }
        }
    }
    __syncthreads();
    #pragma unroll
    for (int rr = 0; rr < 4; ++rr) {
        float* dst = &Rs[w * 2048 + (rg * 4 + rr) * 128 + cg * 8];
        *(float4*)(dst)     = make_float4(acc[rr*8+0], acc[rr*8+1], acc[rr*8+2], acc[rr*8+3]);
        *(float4*)(dst + 4) = make_float4(acc[rr*8+4], acc[rr*8+5], acc[rr*8+6], acc[rr*8+7]);
    }
    __syncthreads();
    const int row = tid >> 4;
    const int c0 = (tid & 15) * 8;
    float s[8];
    #pragma unroll
    for (int e = 0; e < 8; ++e) s[e] = 0.f;
    #pragma unroll
    for (int ww = 0; ww < 4; ++ww) {
        const float* src = &Rs[ww * 2048 + row * 128 + c0];
        float4 a = ((const float4*)src)[0];
        float4 b = ((const float4*)src)[1];
        s[0] += a.x; s[1] += a.y; s[2] += a.z; s[3] += a.w;
        s[4] += b.x; s[5] += b.y; s[6] += b.z; s[7] += b.w;
    }
    const int gcol0 = cc * 128 + c0;
    if (z == 0) {
        float q0 = 0.f, q1 = 0.f;
        #pragma unroll
        for (int e = 0; e < 8; ++e) {
            float t = tanhf(s[e] + ndb[gcol0 + e]);
            float2 ow = ((const float2*)noW)[gcol0 + e];
            q0 = fmaf(t, ow.x, q0);
            q1 = fmaf(t, ow.y, q1);
        }
        #pragma unroll
        for (int off = 8; off > 0; off >>= 1) {
            q0 += __shfl_down(q0, off, 16);
            q1 += __shfl_down(q1, off, 16);
        }
        if ((tid & 15) == 0) {
            float* np = nacc + ((size_t)(rbase + row) * 8 + cc) * 2;
            np[0] = q0; np[1] = q1;
        }
    } else {
        bf16* dstbuf = (z == 1) ? U : V;
        bf16* dst = dstbuf + (size_t)(rbase + row) * 1024 + gcol0;
        #pragma unroll
        for (int e = 0; e < 8; ++e) dst[e] = f2bf(s[e]);
    }
}

// ---------------- k_fin2: sum partials (fallback paths) ----------------
// nacc: [nb*32][8][2] partials; cacc: [nb][16][2]
__global__ __launch_bounds__(256) void k_fin2(const float* __restrict__ nacc,
                                              const float* __restrict__ cacc,
                                              const float* __restrict__ nob,
                                              const float* __restrict__ clsob,
                                              float* __restrict__ out,
                                              int bbase, int nb)
{
    const int idx = blockIdx.x * 256 + threadIdx.x;
    const int R = nb * 32;
    if (idx < R) {
        const float4* p = (const float4*)(nacc + (size_t)idx * 16);
        float4 a = p[0], b4 = p[1], c4 = p[2], d4 = p[3];
        float s0 = a.x + a.z + b4.x + b4.z + c4.x + c4.z + d4.x + d4.z;
        float s1 = a.y + a.w + b4.y + b4.w + c4.y + c4.w + d4.y + d4.w;
        out[32 + bbase * 64 + idx * 2 + 0] = fcf(s0 + nob[0]);
        out[32 + bbase * 64 + idx * 2 + 1] = fcf(s1 + nob[1]);
    } else if (idx < R + nb * 2) {
        const int c = idx - R;
        const int b = c >> 1, l = c & 1;
        float s = 0.f;
        for (int q = 0; q < 16; ++q) s += cacc[(b * 16 + q) * 2 + l];
        out[(bbase + b) * 2 + l] = fcf(s + clsob[l]);
    }
}

// ---------------- k_edge (fallback paths: full compute incl. invalid) ----------------
__global__ __launch_bounds__(256) void k_edge(const bf16* __restrict__ U,
                                              const bf16* __restrict__ V,
                                              const float* __restrict__ edb,
                                              const float* __restrict__ eoW, const float* __restrict__ eob,
                                              const int* __restrict__ po,
                                              float* __restrict__ out,
                                              int bbase)
{
    const int blk = blockIdx.x;
    const int b_loc = blk >> 8;
    const int b = bbase + b_loc;
    const int tid = threadIdx.x;
    const int w = tid >> 6, lane = tid & 63;
    const int e = (blk & 255) * 4 + w;
    const int ps = po_ps(po);
    const int n = count_n(po, b, ps);
    const int m = n + 1;
    const bool valid = e < m * m;
    int i = 0, j = 0;
    if (valid) { i = e / m; j = e - i * m; }
    i = iclamp(i, 0, 31); j = iclamp(j, 0, 31);

    const ushort* urow = (const ushort*)U + (size_t)(b_loc * 32 + j) * 1024;
    const ushort* vrow = (const ushort*)V + (size_t)(b_loc * 32 + i) * 1024;

    float a0 = 0.f, a1 = 0.f;
    #pragma unroll
    for (int c = 0; c < 16; ++c) {
        const int idx = c * 64 + lane;
        float p = edb[idx];
        if (valid) p += us2f(urow[idx]) + us2f(vrow[idx]);
        float t = tanhf(p);
        float2 ow = ((const float2*)eoW)[idx];
        a0 = fmaf(t, ow.x, a0);
        a1 = fmaf(t, ow.y, a1);
    }
    #pragma unroll
    for (int off = 32; off > 0; off >>= 1) {
        a0 += __shfl_down(a0, off, 64);
        a1 += __shfl_down(a1, off, 64);
    }
    if (lane == 0) {
        const size_t o = 32 + 1024 + (size_t)(b * 1024 + e) * 2;
        out[o + 0] = fcf(a0 + eob[0]);
        out[o + 1] = fcf(a1 + eob[1]);
    }
}

// ================= fused C: edge(4096) + fin(3) =================
__global__ __launch_bounds__(256) void k_fusedC(const bf16* __restrict__ U,
                                                const bf16* __restrict__ V,
                                                const float* __restrict__ nacc,
                                                const float* __restrict__ cacc,
                                                const float* __restrict__ nob,
                                                const float* __restrict__ clsob,
                                                const float* __restrict__ edb,
                                                const float* __restrict__ eoW,
                                                const float* __restrict__ eob,
                                                const float* __restrict__ econ,
                                                const int* __restrict__ po,
                                                float* __restrict__ out)
{
    const int blk = blockIdx.x;
    const int tid = threadIdx.x;

    if (blk >= 4096) {                                  // fin blocks
        const int idx = (blk - 4096) * 256 + tid;
        if (idx < 512) {
            const float4* p = (const float4*)(nacc + (size_t)idx * 16);
            float4 a = p[0], b4 = p[1], c4 = p[2], d4 = p[3];
            float s0 = a.x + a.z + b4.x + b4.z + c4.x + c4.z + d4.x + d4.z;
            float s1 = a.y + a.w + b4.y + b4.w + c4.y + c4.w + d4.y + d4.w;
            out[32 + idx * 2 + 0] = fcf(s0 + nob[0]);
            out[32 + idx * 2 + 1] = fcf(s1 + nob[1]);
        } else if (idx < 544) {
            const int c = idx - 512;
            const int b = c >> 1, l = c & 1;
            float s = 0.f;
            for (int q = 0; q < 16; ++q) s += cacc[(b * 16 + q) * 2 + l];
            out[b * 2 + l] = fcf(s + clsob[l]);
        }
        return;
    }

    // edge blocks
    const int b = blk >> 8;
    const int w = tid >> 6, lane = tid & 63;
    const int e = (blk & 255) * 4 + w;
    const int ps = po_ps(po);
    const int n = count_n(po, b, ps);
    const int m = n + 1;
    const size_t o = 32 + 1024 + (size_t)(b * 1024 + e) * 2;

    if (e >= m * m) {                                   // invalid: precomputed constant
        if (lane == 0) {
            out[o + 0] = fcf(econ[0] + eob[0]);
            out[o + 1] = fcf(econ[1] + eob[1]);
        }
        return;
    }

    int i = e / m, j = e - i * m;
    i = iclamp(i, 0, 31); j = iclamp(j, 0, 31);
    const ushort* urow = (const ushort*)U + (size_t)(b * 32 + j) * 1024;
    const ushort* vrow = (const ushort*)V + (size_t)(b * 32 + i) * 1024;

    float a0 = 0.f, a1 = 0.f;
    #pragma unroll
    for (int c = 0; c < 16; ++c) {
        const int idx = c * 64 + lane;
        float p = edb[idx] + us2f(urow[idx]) + us2f(vrow[idx]);
        float t = tanhf(p);
        float2 ow = ((const float2*)eoW)[idx];
        a0 = fmaf(t, ow.x, a0);
        a1 = fmaf(t, ow.y, a1);
    }
    #pragma unroll
    for (int off = 32; off > 0; off >>= 1) {
        a0 += __shfl_down(a0, off, 64);
        a1 += __shfl_down(a1, off, 64);
    }
    if (lane == 0) {
        out[o + 0] = fcf(a0 + eob[0]);
        out[o + 1] = fcf(a1 + eob[1]);
    }
}

extern "C" void kernel_launch(void* const* d_in, const int* in_sizes, int n_in,
                              void* d_out, int out_size, void* d_ws, size_t ws_size,
                              hipStream_t stream) {
    (void)out_size;
    float* out = (float*)d_out;

    bool ok = (n_in >= 16)
        && in_sizes[0] == 8388608 && in_sizes[1] == 512
        && in_sizes[2] == 1048576 && in_sizes[3] == 1024
        && in_sizes[4] == 1048576 && in_sizes[5] == 1024
        && in_sizes[6] == 2048    && in_sizes[7] == 2
        && in_sizes[8] == 1048576 && in_sizes[9] == 1024
        && in_sizes[10] == 2048   && in_sizes[11] == 2
        && in_sizes[12] == 3145728 && in_sizes[13] == 1024
        && in_sizes[14] == 2048   && in_sizes[15] == 2;
    if (!ok) {
        hipLaunchKernelGGL(k_sentinel, dim3(133), dim3(256), 0, stream, out, 33824, 111.0f);
        return;
    }

    const float* seq   = (const float*)d_in[0];
    const int*   po    = (const int*)d_in[1];
    const float* nafW  = (const float*)d_in[2];
    const float* nafb  = (const float*)d_in[3];
    const float* clsW  = (const float*)d_in[4];
    const float* clsb  = (const float*)d_in[5];
    const float* clsoW = (const float*)d_in[6];
    const float* clsob = (const float*)d_in[7];
    const float* ndW   = (const float*)d_in[8];
    const float* ndb   = (const float*)d_in[9];
    const float* noW   = (const float*)d_in[10];
    const float* nob   = (const float*)d_in[11];
    const float* eW    = (const float*)d_in[12];
    const float* edb   = (const float*)d_in[13];
    const float* eoW   = (const float*)d_in[14];
    const float* eob   = (const float*)d_in[15];

    char* ws = (char*)d_ws;

    const size_t fnB   = (size_t)512 * 1024 * 2;                // 1 MB per bf16 buffer
    const size_t naccB = (size_t)512 * 8 * 2 * sizeof(float);   // 32 KB partials
    const size_t caccB = (size_t)16 * 16 * 2 * sizeof(float);   // 2 KB partials
    const size_t econB = 64;                                    // 2 floats, padded
    const size_t wctB  = (size_t)3 * 1024 * 1024 * 2;           // 6 MB bf16 Wct
    const size_t needA = 3 * fnB + naccB + caccB + econB + wctB;
    const size_t needB = 3 * fnB + naccB + caccB;
    const size_t fnC   = (size_t)32 * 1024 * 2;
    const size_t needC = 3 * fnC + (size_t)32 * 8 * 2 * sizeof(float) + (size_t)16 * 2 * sizeof(float);

    if (ws_size >= needA) {
        bf16*   fn   = (bf16*)(ws);
        bf16*   U    = (bf16*)(ws + fnB);
        bf16*   V    = (bf16*)(ws + 2 * fnB);
        float*  nacc = (float*)(ws + 3 * fnB);
        float*  cacc = (float*)(ws + 3 * fnB + naccB);
        float*  econ = (float*)(ws + 3 * fnB + naccB + caccB);
        ushort* Wct  = (ushort*)(ws + 3 * fnB + naccB + caccB + econB);
        hipLaunchKernelGGL(k_fusedA, dim3(3841), dim3(256), 0, stream,
                           seq, po, nafW, nafb, clsW, clsb, clsoW, ndW, eW, edb, eoW,
                           fn, cacc, Wct, econ);
        hipLaunchKernelGGL(k_huv_mfma, dim3(768), dim3(256), 0, stream,
                           fn, Wct, ndb, noW, nacc, U, V);
        hipLaunchKernelGGL(k_fusedC, dim3(4099), dim3(256), 0, stream,
                           U, V, nacc, cacc, nob, clsob, edb, eoW, eob, econ, po, out);
    } else if (ws_size >= needB) {
        bf16*  fn   = (bf16*)(ws);
        bf16*  U    = (bf16*)(ws + fnB);
        bf16*  V    = (bf16*)(ws + 2 * fnB);
        float* nacc = (float*)(ws + 3 * fnB);
        float* cacc = (float*)(ws + 3 * fnB + naccB);
        hipLaunchKernelGGL(k_nodes, dim3(512), dim3(256), 0, stream, seq, po, fn, 0);
        hipLaunchKernelGGL(k_cls, dim3(16, 16), dim3(256), 0, stream,
                           seq, po, nafW, nafb, clsW, clsb, clsoW, fn, cacc, 0);
        hipLaunchKernelGGL(k_huv_valu, dim3(32, 8, 3), dim3(256), 0, stream,
                           fn, ndW, ndb, noW, eW, nacc, U, V);
        hipLaunchKernelGGL(k_fin2, dim3(3), dim3(256), 0, stream, nacc, cacc, nob, clsob, out, 0, 16);
        hipLaunchKernelGGL(k_edge, dim3(4096), dim3(256), 0, stream,
                           U, V, edb, eoW, eob, po, out, 0);
    } else if (ws_size >= needC) {
        bf16*  fn   = (bf16*)(ws);
        bf16*  U    = (bf16*)(ws + fnC);
        bf16*  V    = (bf16*)(ws + 2 * fnC);
        float* nacc = (float*)(ws + 3 * fnC);
        float* cacc = nacc + 32 * 8 * 2;
        for (int b = 0; b < 16; ++b) {
            hipLaunchKernelGGL(k_nodes, dim3(32), dim3(256), 0, stream, seq, po, fn, b);
            hipLaunchKernelGGL(k_cls, dim3(1, 16), dim3(256), 0, stream,
                               seq, po, nafW, nafb, clsW, clsb, clsoW, fn, cacc, b);
            hipLaunchKernelGGL(k_huv_valu, dim3(2, 8, 3), dim3(256), 0, stream,
                               fn, ndW, ndb, noW, eW, nacc, U, V);
            hipLaunchKernelGGL(k_fin2, dim3(1), dim3(256), 0, stream, nacc, cacc, nob, clsob, out, b, 1);
            hipLaunchKernelGGL(k_edge, dim3(256), dim3(256), 0, stream,
                               U, V, edb, eoW, eob, po, out, b);
        }
    } else {
        hipLaunchKernelGGL(k_sentinel, dim3(133), dim3(256), 0, stream, out, 33824, 222.0f);
    }
}

// Round 9
// 178.798 us; speedup vs baseline: 1.0248x; 1.0248x over previous
//
#include <hip/hip_runtime.h>
#include <hip/hip_bf16.h>

typedef __hip_bfloat16 bf16;
typedef unsigned short ushort;
typedef __attribute__((ext_vector_type(8))) short short8v;   // bf16x8 MFMA frag
typedef __attribute__((ext_vector_type(4))) float float4v;   // fp32x4 MFMA acc

__device__ __forceinline__ float us2f(unsigned int u) {
    union { unsigned int i; float f; } c; c.i = u << 16; return c.f;
}
__device__ __forceinline__ bf16 f2bf(float x) { return __float2bfloat16(x); }
__device__ __forceinline__ ushort f2bfu(float x) {
    union { float f; unsigned int i; } c; c.f = x;
    unsigned int lsb = (c.i >> 16) & 1;
    return (ushort)((c.i + 0x7FFF + lsb) >> 16);
}
__device__ __forceinline__ float fcf(float x) {               // out f32, clamp NaN
    return fminf(1000.f, fmaxf(-1000.f, x));
}
__device__ __forceinline__ int iclamp(int v, int lo, int hi) {
    return v < lo ? lo : (v > hi ? hi : v);
}

// B=16, S=512, H=1024, K=32 slots, E=1024, L=2
// inputs f32; po int32-or-int64 (detected); out f32: cls[32] | node[1024] | edge[32768]
__device__ __forceinline__ int po_ps(const int* po) {
    return ((po[1] | po[3] | po[5]) == 0) ? 2 : 1;
}
__device__ __forceinline__ int count_n(const int* po, int b, int ps) {
    int n = 0;
    #pragma unroll
    for (int j = 1; j < 32; ++j) n += (po[(b * 32 + j) * ps] > 0) ? 1 : 0;
    return iclamp(n, 0, 31);
}

__global__ __launch_bounds__(256) void k_sentinel(float* __restrict__ out, int nv, float val) {
    int i = blockIdx.x * 256 + threadIdx.x;
    if (i < nv) out[i] = val;
}

// ================= device phase functions =================

// prep: Wct[z][n][k] = combined, transposed, bf16. z=0: ndW^T; z=1: (W1+W3)^T; z=2: (W2-W3)^T
__device__ __forceinline__ void dev_prep(int kt, int nt, int z, int tid,
                                         const float* __restrict__ ndW,
                                         const float* __restrict__ eW,
                                         ushort* __restrict__ Wct, float* smemf)
{
    float (*T)[33] = (float (*)[33])smemf;          // 32x33 = 1056 floats

    const int k_loc = tid >> 3, n0 = (tid & 7) * 4;
    const size_t gofs = (size_t)(kt * 32 + k_loc) * 1024 + nt * 32 + n0;
    float4 v;
    if (z == 0) {
        v = *(const float4*)(ndW + gofs);
    } else if (z == 1) {
        float4 a = *(const float4*)(eW + gofs);
        float4 b = *(const float4*)(eW + (size_t)2048 * 1024 + gofs);
        v = make_float4(a.x + b.x, a.y + b.y, a.z + b.z, a.w + b.w);
    } else {
        float4 a = *(const float4*)(eW + (size_t)1024 * 1024 + gofs);
        float4 b = *(const float4*)(eW + (size_t)2048 * 1024 + gofs);
        v = make_float4(a.x - b.x, a.y - b.y, a.z - b.z, a.w - b.w);
    }
    T[k_loc][n0 + 0] = v.x; T[k_loc][n0 + 1] = v.y;
    T[k_loc][n0 + 2] = v.z; T[k_loc][n0 + 3] = v.w;
    __syncthreads();

    const int n_loc = tid >> 3, k0 = (tid & 7) * 4;
    ushort* dst = Wct + (size_t)z * 1024 * 1024 + (size_t)(nt * 32 + n_loc) * 1024 + kt * 32 + k0;
    ushort4 o;
    o.x = f2bfu(T[k0 + 0][n_loc]); o.y = f2bfu(T[k0 + 1][n_loc]);
    o.z = f2bfu(T[k0 + 2][n_loc]); o.w = f2bfu(T[k0 + 3][n_loc]);
    *(ushort4*)dst = o;
}

// nodes: segment means -> fn rows k != n  (row n is written by cls/naf)
// unroll-by-2 with independent accumulators: 2 loads in flight per thread
__device__ __forceinline__ void dev_nodes(int bx, int tid,
                                          const float* __restrict__ seq,
                                          const int* __restrict__ po,
                                          bf16* __restrict__ fn, int bbase)
{
    const int b_loc = bx >> 5;
    const int k = bx & 31;
    const int b = bbase + b_loc;
    const int ps = po_ps(po);
    const int n = count_n(po, b, ps);
    if (k == n) return;                               // naf row: cls phase writes it

    const int h0 = tid * 4;
    float4 acc = make_float4(0.f, 0.f, 0.f, 0.f);
    if (k < n) {
        int s_end   = iclamp(po[(b * 32 + k + 1) * ps], 1, 511);
        int s_begin = (k == 0) ? 1 : iclamp(po[(b * 32 + k) * ps] + 1, 1, 511);
        if (s_end < s_begin) s_end = s_begin;
        const float inv = 1.0f / (float)(s_end - s_begin + 1);
        float4 acc2 = make_float4(0.f, 0.f, 0.f, 0.f);
        int s = s_begin;
        const float* base = seq + (size_t)b * 524288 + h0;
        for (; s + 1 <= s_end; s += 2) {
            float4 u = *(const float4*)(base + (size_t)s * 1024);
            float4 v = *(const float4*)(base + (size_t)(s + 1) * 1024);
            acc.x += u.x;  acc.y += u.y;  acc.z += u.z;  acc.w += u.w;
            acc2.x += v.x; acc2.y += v.y; acc2.z += v.z; acc2.w += v.w;
        }
        if (s <= s_end) {
            float4 u = *(const float4*)(base + (size_t)s * 1024);
            acc.x += u.x; acc.y += u.y; acc.z += u.z; acc.w += u.w;
        }
        acc.x = (acc.x + acc2.x) * inv; acc.y = (acc.y + acc2.y) * inv;
        acc.z = (acc.z + acc2.z) * inv; acc.w = (acc.w + acc2.w) * inv;
    }
    bf16* dst = fn + (size_t)(b_loc * 32 + k) * 1024 + h0;
    dst[0] = f2bf(acc.x); dst[1] = f2bf(acc.y); dst[2] = f2bf(acc.z); dst[3] = f2bf(acc.w);
}

// cls: cls head partials (no atomics) + naf row of fn.
// Restructured for latency: thread (c16,kq) owns 4 cols (float4 W loads) x K-chunk of 64.
// 16-way K split, 2x16B loads/iter, unroll 4 -> deep VMEM pipeline.
__device__ __forceinline__ void dev_cls(int b_loc, int q, int tid,
                                        const float* __restrict__ seq,
                                        const int* __restrict__ po,
                                        const float* __restrict__ nafW, const float* __restrict__ nafb,
                                        const float* __restrict__ clsW, const float* __restrict__ clsb,
                                        const float* __restrict__ clsoW,
                                        bf16* __restrict__ fn,
                                        float* __restrict__ cacc,      // [16][16][2] partials
                                        int bbase, float* smemf)
{
    const int b = bbase + b_loc;
    float* xs   = smemf;                              // 1024 floats
    float* redc = smemf + 1024;                       // 16 kq x 64 cols
    float* redn = smemf + 2048;                       // 16 kq x 64 cols
    for (int j = tid; j < 1024; j += 256) xs[j] = seq[(size_t)b * 524288 + j];
    __syncthreads();

    const int c16 = tid & 15, kq = tid >> 4;          // 16 col-groups x 16 K-chunks
    const int col0 = q * 64 + c16 * 4;
    const int kb = kq * 64;
    const float* wc_base = clsW + (size_t)kb * 1024 + col0;
    const float* wn_base = nafW + (size_t)kb * 1024 + col0;
    float4 ac = make_float4(0.f, 0.f, 0.f, 0.f);
    float4 an = make_float4(0.f, 0.f, 0.f, 0.f);
    #pragma unroll 4
    for (int i = 0; i < 64; ++i) {
        const float x = xs[kb + i];
        float4 wc = *(const float4*)(wc_base + (size_t)i * 1024);
        float4 wn = *(const float4*)(wn_base + (size_t)i * 1024);
        ac.x = fmaf(x, wc.x, ac.x); ac.y = fmaf(x, wc.y, ac.y);
        ac.z = fmaf(x, wc.z, ac.z); ac.w = fmaf(x, wc.w, ac.w);
        an.x = fmaf(x, wn.x, an.x); an.y = fmaf(x, wn.y, an.y);
        an.z = fmaf(x, wn.z, an.z); an.w = fmaf(x, wn.w, an.w);
    }
    *(float4*)&redc[kq * 64 + c16 * 4] = ac;
    *(float4*)&redn[kq * 64 + c16 * 4] = an;
    __syncthreads();

    if (tid < 64) {
        const int cl = tid;
        float cs = 0.f, ns = 0.f;
        #pragma unroll
        for (int kk = 0; kk < 16; ++kk) {
            cs += redc[kk * 64 + cl];
            ns += redn[kk * 64 + cl];
        }
        const int hout = q * 64 + cl;
        const int ps = po_ps(po);
        const int n = count_n(po, b, ps);
        fn[(size_t)(b_loc * 32 + n) * 1024 + hout] = f2bf(ns + nafb[hout]);
        float h = tanhf(cs + clsb[hout]);
        float2 ow = ((const float2*)clsoW)[hout];
        float q0 = h * ow.x, q1 = h * ow.y;
        #pragma unroll
        for (int off = 32; off > 0; off >>= 1) {
            q0 += __shfl_down(q0, off, 64);
            q1 += __shfl_down(q1, off, 64);
        }
        if (cl == 0) {
            cacc[(b_loc * 16 + q) * 2 + 0] = q0;
            cacc[(b_loc * 16 + q) * 2 + 1] = q1;
        }
    }
}

// econ: invalid-edge constant (bit-identical to k_edge's invalid-wave computation)
__device__ __forceinline__ void dev_econ(int tid,
                                         const float* __restrict__ edb,
                                         const float* __restrict__ eoW,
                                         float* __restrict__ econ)
{
    if (tid >= 64) return;
    const int lane = tid;
    float a0 = 0.f, a1 = 0.f;
    #pragma unroll
    for (int c = 0; c < 16; ++c) {
        const int idx = c * 64 + lane;
        float t = tanhf(edb[idx]);
        float2 ow = ((const float2*)eoW)[idx];
        a0 = fmaf(t, ow.x, a0);
        a1 = fmaf(t, ow.y, a1);
    }
    #pragma unroll
    for (int off = 32; off > 0; off >>= 1) {
        a0 += __shfl_down(a0, off, 64);
        a1 += __shfl_down(a1, off, 64);
    }
    if (lane == 0) { econ[0] = a0; econ[1] = a1; }
}

// ================= fused A: cls(256) | nodes(512) | prep(3072) | econ(1) =================
// Latency-bound phases (cls, nodes) dispatched first; high-TLP prep fills the machine behind.
__global__ __launch_bounds__(256) void k_fusedA(const float* __restrict__ seq,
                                                const int* __restrict__ po,
                                                const float* __restrict__ nafW, const float* __restrict__ nafb,
                                                const float* __restrict__ clsW, const float* __restrict__ clsb,
                                                const float* __restrict__ clsoW,
                                                const float* __restrict__ ndW,
                                                const float* __restrict__ eW,
                                                const float* __restrict__ edb,
                                                const float* __restrict__ eoW,
                                                bf16* __restrict__ fn,
                                                float* __restrict__ cacc,
                                                ushort* __restrict__ Wct,
                                                float* __restrict__ econ)
{
    __shared__ __align__(16) float smem[3072];
    const int blk = blockIdx.x;
    const int tid = threadIdx.x;
    if (blk < 256) {
        dev_cls(blk & 15, blk >> 4, tid, seq, po, nafW, nafb, clsW, clsb, clsoW, fn, cacc, 0, smem);
    } else if (blk < 768) {
        dev_nodes(blk - 256, tid, seq, po, fn, 0);
    } else if (blk < 3840) {
        const int rem = blk - 768;
        const int z = rem >> 10, t10 = rem & 1023;
        dev_prep(t10 & 31, t10 >> 5, z, tid, ndW, eW, Wct, smem);
    } else {
        dev_econ(tid, edb, eoW, econ);
    }
}

// standalone wrappers (fallback paths)
__global__ __launch_bounds__(256) void k_nodes(const float* __restrict__ seq,
                                               const int* __restrict__ po,
                                               bf16* __restrict__ fn, int bbase)
{
    dev_nodes(blockIdx.x, threadIdx.x, seq, po, fn, bbase);
}
__global__ __launch_bounds__(256) void k_cls(const float* __restrict__ seq,
                                             const int* __restrict__ po,
                                             const float* __restrict__ nafW, const float* __restrict__ nafb,
                                             const float* __restrict__ clsW, const float* __restrict__ clsb,
                                             const float* __restrict__ clsoW,
                                             bf16* __restrict__ fn,
                                             float* __restrict__ cacc, int bbase)
{
    __shared__ __align__(16) float smem[3072];
    dev_cls(blockIdx.x, blockIdx.y, threadIdx.x, seq, po, nafW, nafb, clsW, clsb, clsoW, fn, cacc, bbase, smem);
}

// ---------------- k_huv_mfma: fn(16 rows) @ Wct[z] via 16x16x32 bf16 MFMA ----------------
// grid (nb*2 rt, 8 cc of 128 cols, 3 z), block 256 = 4 waves; wave w owns 32 cols.
// z==0 writes per-(row,cc) partials into nacc[512][8][2] (no atomics).
__global__ __launch_bounds__(256) void k_huv_mfma(const bf16* __restrict__ X,
                                                  const ushort* __restrict__ Wct,
                                                  const float* __restrict__ ndb,
                                                  const float* __restrict__ noW,
                                                  float* __restrict__ nacc,
                                                  bf16* __restrict__ U,
                                                  bf16* __restrict__ V)
{
    const int rt = blockIdx.x;
    const int cc = blockIdx.y;
    const int z  = blockIdx.z;
    const int tid = threadIdx.x;
    const int w = tid >> 6, lane = tid & 63;
    const int quad = lane >> 4, l16 = lane & 15;
    const int rbase = rt * 16;

    __shared__ char smem[32768];
    short* A_lds = (short*)smem;          // frag-order A: slot((ks>>5), quad, m) * 8 bf16
    float* Rs    = (float*)smem;          // 16 x 128 f32 epilogue buffer (aliases A)

    // stage A (16 rows x 1024 K) in MFMA fragment order
    {
        const int r = tid >> 4, s = tid & 15;
        const ushort* src = (const ushort*)X + (size_t)(rbase + r) * 1024 + s * 64;
        #pragma unroll
        for (int cch = 0; cch < 8; ++cch) {
            const int k0 = s * 64 + cch * 8;
            uint4 v = *(const uint4*)(src + cch * 8);
            const int slot = ((k0 >> 5) * 64 + ((k0 >> 3) & 3) * 16 + r) * 8;
            *(uint4*)&A_lds[slot] = v;
        }
    }
    __syncthreads();

    const ushort* Wz = Wct + (size_t)z * 1024 * 1024;
    const int nbase = cc * 128 + w * 32;
    const ushort* B0 = Wz + (size_t)(nbase + l16) * 1024 + quad * 8;
    const ushort* B1 = B0 + (size_t)16 * 1024;

    float4v acc0 = {0.f, 0.f, 0.f, 0.f};
    float4v acc1 = {0.f, 0.f, 0.f, 0.f};

    #pragma unroll 4
    for (int ks = 0; ks < 1024; ks += 32) {
        short8v a  = *(const short8v*)&A_lds[((ks >> 5) * 64 + quad * 16 + l16) * 8];
        short8v b0 = *(const short8v*)(B0 + ks);
        short8v b1 = *(const short8v*)(B1 + ks);
        acc0 = __builtin_amdgcn_mfma_f32_16x16x32_bf16(a, b0, acc0, 0, 0, 0);
        acc1 = __builtin_amdgcn_mfma_f32_16x16x32_bf16(a, b1, acc1, 0, 0, 0);
    }
    __syncthreads();                      // A dead; reuse as Rs

    // C/D layout: row = quad*4 + reg, col = l16 (verified m89)
    #pragma unroll
    for (int reg = 0; reg < 4; ++reg) {
        Rs[(quad * 4 + reg) * 128 + w * 32 + l16]      = acc0[reg];
        Rs[(quad * 4 + reg) * 128 + w * 32 + 16 + l16] = acc1[reg];
    }
    __syncthreads();

    const int row = tid >> 4;
    const int c0 = (tid & 15) * 8;
    const int gcol0 = cc * 128 + c0;
    const float* src = &Rs[row * 128 + c0];
    float s[8];
    {
        float4 a = ((const float4*)src)[0];
        float4 b = ((const float4*)src)[1];
        s[0] = a.x; s[1] = a.y; s[2] = a.z; s[3] = a.w;
        s[4] = b.x; s[5] = b.y; s[6] = b.z; s[7] = b.w;
    }
    if (z == 0) {
        float q0 = 0.f, q1 = 0.f;
        #pragma unroll
        for (int e = 0; e < 8; ++e) {
            float t = tanhf(s[e] + ndb[gcol0 + e]);
            float2 ow = ((const float2*)noW)[gcol0 + e];
            q0 = fmaf(t, ow.x, q0);
            q1 = fmaf(t, ow.y, q1);
        }
        #pragma unroll
        for (int off = 8; off > 0; off >>= 1) {
            q0 += __shfl_down(q0, off, 16);
            q1 += __shfl_down(q1, off, 16);
        }
        if ((tid & 15) == 0) {
            float* np = nacc + ((size_t)(rbase + row) * 8 + cc) * 2;
            np[0] = q0; np[1] = q1;
        }
    } else {
        bf16* dstbuf = (z == 1) ? U : V;
        bf16* dst = dstbuf + (size_t)(rbase + row) * 1024 + gcol0;
        #pragma unroll
        for (int e = 0; e < 8; ++e) dst[e] = f2bf(s[e]);
    }
}

// ---------------- k_huv_valu: fallback (ws too small for Wct) ----------------
__global__ __launch_bounds__(256) void k_huv_valu(const bf16* __restrict__ X,
                                                  const float* __restrict__ ndW, const float* __restrict__ ndb,
                                                  const float* __restrict__ noW,
                                                  const float* __restrict__ eW,
                                                  float* __restrict__ nacc,
                                                  bf16* __restrict__ U,
                                                  bf16* __restrict__ V)
{
    const int rt = blockIdx.x, cc = blockIdx.y, z = blockIdx.z;
    const int tid = threadIdx.x;
    const int w = tid >> 6, lane = tid & 63;
    const int rg = lane >> 4, cg = lane & 15;
    const int rbase = rt * 16;
    const int colb = cc * 128 + cg * 8;

    __shared__ float LDSb[8192];
    float* Xs = LDSb;
    float* Rs = LDSb;

    const float* W0;
    const float* W1 = nullptr;
    float sgn = 1.f;
    if (z == 0)      { W0 = ndW; }
    else if (z == 1) { W0 = eW; W1 = eW + (size_t)2048 * 1024; }
    else             { W0 = eW + (size_t)1024 * 1024; W1 = eW + (size_t)2048 * 1024; sgn = -1.f; }

    float acc[32];
    #pragma unroll
    for (int i = 0; i < 32; ++i) acc[i] = 0.f;

    const int sr = tid & 15, sq0 = tid >> 4;
    const ushort* Xu = (const ushort*)X;

    for (int ks = 0; ks < 1024; ks += 256) {
        __syncthreads();
        #pragma unroll
        for (int it = 0; it < 4; ++it) {
            int qq = sq0 + it * 16;
            ushort4 xv = *(const ushort4*)(Xu + (size_t)(rbase + sr) * 1024 + ks + qq * 4);
            int kk = qq * 4;
            Xs[(kk + 0) * 16 + sr] = us2f(xv.x);
            Xs[(kk + 1) * 16 + sr] = us2f(xv.y);
            Xs[(kk + 2) * 16 + sr] = us2f(xv.z);
            Xs[(kk + 3) * 16 + sr] = us2f(xv.w);
        }
        __syncthreads();
        const int k0 = ks + w * 64;
        for (int kk = 0; kk < 64; ++kk) {
            float4 xv = *(const float4*)&Xs[(w * 64 + kk) * 16 + rg * 4];
            const float* wp0 = W0 + (size_t)(k0 + kk) * 1024 + colb;
            float4 wa = ((const float4*)wp0)[0];
            float4 wb = ((const float4*)wp0)[1];
            if (W1) {
                const float* wp1 = W1 + (size_t)(k0 + kk) * 1024 + colb;
                float4 va = ((const float4*)wp1)[0];
                float4 vb = ((const float4*)wp1)[1];
                wa.x = fmaf(sgn, va.x, wa.x); wa.y = fmaf(sgn, va.y, wa.y);
                wa.z = fmaf(sgn, va.z, wa.z); wa.w = fmaf(sgn, va.w, wa.w);
                wb.x = fmaf(sgn, vb.x, wb.x); wb.y = fmaf(sgn, vb.y, wb.y);
                wb.z = fmaf(sgn, vb.z, wb.z); wb.w = fmaf(sgn, vb.w, wb.w);
            }
            float xr[4] = {xv.x, xv.y, xv.z, xv.w};
            #pragma unroll
            for (int rr = 0; rr < 4; ++rr) {
                acc[rr*8+0] = fmaf(xr[rr], wa.x, acc[rr*8+0]);
                acc[rr*8+1] = fmaf(xr[rr], wa.y, acc[rr*8+1]);
                acc[rr*8+2] = fmaf(xr[rr], wa.z, acc[rr*8+2]);
                acc[rr*8+3] = fmaf(xr[rr], wa.w, acc[rr*8+3]);
                acc[rr*8+4] = fmaf(xr[rr], wb.x, acc[rr*8+4]);
                acc[rr*8+5] = fmaf(xr[rr], wb.y, acc[rr*8+5]);
                acc[rr*8+6] = fmaf(xr[rr], wb.z, acc[rr*8+6]);
                acc[rr*8+7] = fmaf(xr[rr], wb.w, acc[rr*8+7]);
            }
        }
    }
    __syncthreads();
    #pragma unroll
    for (int rr = 0; rr < 4; ++rr) {
        float* dst = &Rs[w * 2048 + (rg * 4 + rr) * 128 + cg * 8];
        *(float4*)(dst)     = make_float4(acc[rr*8+0], acc[rr*8+1], acc[rr*8+2], acc[rr*8+3]);
        *(float4*)(dst + 4) = make_float4(acc[rr*8+4], acc[rr*8+5], acc[rr*8+6], acc[rr*8+7]);
    }
    __syncthreads();
    const int row = tid >> 4;
    const int c0 = (tid & 15) * 8;
    float s[8];
    #pragma unroll
    for (int e = 0; e < 8; ++e) s[e] = 0.f;
    #pragma unroll
    for (int ww = 0; ww < 4; ++ww) {
        const float* src = &Rs[ww * 2048 + row * 128 + c0];
        float4 a = ((const float4*)src)[0];
        float4 b = ((const float4*)src)[1];
        s[0] += a.x; s[1] += a.y; s[2] += a.z; s[3] += a.w;
        s[4] += b.x; s[5] += b.y; s[6] += b.z; s[7] += b.w;
    }
    const int gcol0 = cc * 128 + c0;
    if (z == 0) {
        float q0 = 0.f, q1 = 0.f;
        #pragma unroll
        for (int e = 0; e < 8; ++e) {
            float t = tanhf(s[e] + ndb[gcol0 + e]);
            float2 ow = ((const float2*)noW)[gcol0 + e];
            q0 = fmaf(t, ow.x, q0);
            q1 = fmaf(t, ow.y, q1);
        }
        #pragma unroll
        for (int off = 8; off > 0; off >>= 1) {
            q0 += __shfl_down(q0, off, 16);
            q1 += __shfl_down(q1, off, 16);
        }
        if ((tid & 15) == 0) {
            float* np = nacc + ((size_t)(rbase + row) * 8 + cc) * 2;
            np[0] = q0; np[1] = q1;
        }
    } else {
        bf16* dstbuf = (z == 1) ? U : V;
        bf16* dst = dstbuf + (size_t)(rbase + row) * 1024 + gcol0;
        #pragma unroll
        for (int e = 0; e < 8; ++e) dst[e] = f2bf(s[e]);
    }
}

// ---------------- k_fin2: sum partials (fallback paths) ----------------
// nacc: [nb*32][8][2] partials; cacc: [nb][16][2]
__global__ __launch_bounds__(256) void k_fin2(const float* __restrict__ nacc,
                                              const float* __restrict__ cacc,
                                              const float* __restrict__ nob,
                                              const float* __restrict__ clsob,
                                              float* __restrict__ out,
                                              int bbase, int nb)
{
    const int idx = blockIdx.x * 256 + threadIdx.x;
    const int R = nb * 32;
    if (idx < R) {
        const float4* p = (const float4*)(nacc + (size_t)idx * 16);
        float4 a = p[0], b4 = p[1], c4 = p[2], d4 = p[3];
        float s0 = a.x + a.z + b4.x + b4.z + c4.x + c4.z + d4.x + d4.z;
        float s1 = a.y + a.w + b4.y + b4.w + c4.y + c4.w + d4.y + d4.w;
        out[32 + bbase * 64 + idx * 2 + 0] = fcf(s0 + nob[0]);
        out[32 + bbase * 64 + idx * 2 + 1] = fcf(s1 + nob[1]);
    } else if (idx < R + nb * 2) {
        const int c = idx - R;
        const int b = c >> 1, l = c & 1;
        float s = 0.f;
        for (int q = 0; q < 16; ++q) s += cacc[(b * 16 + q) * 2 + l];
        out[(bbase + b) * 2 + l] = fcf(s + clsob[l]);
    }
}

// ---------------- k_edge (fallback paths: full compute incl. invalid) ----------------
__global__ __launch_bounds__(256) void k_edge(const bf16* __restrict__ U,
                                              const bf16* __restrict__ V,
                                              const float* __restrict__ edb,
                                              const float* __restrict__ eoW, const float* __restrict__ eob,
                                              const int* __restrict__ po,
                                              float* __restrict__ out,
                                              int bbase)
{
    const int blk = blockIdx.x;
    const int b_loc = blk >> 8;
    const int b = bbase + b_loc;
    const int tid = threadIdx.x;
    const int w = tid >> 6, lane = tid & 63;
    const int e = (blk & 255) * 4 + w;
    const int ps = po_ps(po);
    const int n = count_n(po, b, ps);
    const int m = n + 1;
    const bool valid = e < m * m;
    int i = 0, j = 0;
    if (valid) { i = e / m; j = e - i * m; }
    i = iclamp(i, 0, 31); j = iclamp(j, 0, 31);

    const ushort* urow = (const ushort*)U + (size_t)(b_loc * 32 + j) * 1024;
    const ushort* vrow = (const ushort*)V + (size_t)(b_loc * 32 + i) * 1024;

    float a0 = 0.f, a1 = 0.f;
    #pragma unroll
    for (int c = 0; c < 16; ++c) {
        const int idx = c * 64 + lane;
        float p = edb[idx];
        if (valid) p += us2f(urow[idx]) + us2f(vrow[idx]);
        float t = tanhf(p);
        float2 ow = ((const float2*)eoW)[idx];
        a0 = fmaf(t, ow.x, a0);
        a1 = fmaf(t, ow.y, a1);
    }
    #pragma unroll
    for (int off = 32; off > 0; off >>= 1) {
        a0 += __shfl_down(a0, off, 64);
        a1 += __shfl_down(a1, off, 64);
    }
    if (lane == 0) {
        const size_t o = 32 + 1024 + (size_t)(b * 1024 + e) * 2;
        out[o + 0] = fcf(a0 + eob[0]);
        out[o + 1] = fcf(a1 + eob[1]);
    }
}

// ================= fused C: edge(4096) + fin(3) =================
__global__ __launch_bounds__(256) void k_fusedC(const bf16* __restrict__ U,
                                                const bf16* __restrict__ V,
                                                const float* __restrict__ nacc,
                                                const float* __restrict__ cacc,
                                                const float* __restrict__ nob,
                                                const float* __restrict__ clsob,
                                                const float* __restrict__ edb,
                                                const float* __restrict__ eoW,
                                                const float* __restrict__ eob,
                                                const float* __restrict__ econ,
                                                const int* __restrict__ po,
                                                float* __restrict__ out)
{
    const int blk = blockIdx.x;
    const int tid = threadIdx.x;

    if (blk >= 4096) {                                  // fin blocks
        const int idx = (blk - 4096) * 256 + tid;
        if (idx < 512) {
            const float4* p = (const float4*)(nacc + (size_t)idx * 16);
            float4 a = p[0], b4 = p[1], c4 = p[2], d4 = p[3];
            float s0 = a.x + a.z + b4.x + b4.z + c4.x + c4.z + d4.x + d4.z;
            float s1 = a.y + a.w + b4.y + b4.w + c4.y + c4.w + d4.y + d4.w;
            out[32 + idx * 2 + 0] = fcf(s0 + nob[0]);
            out[32 + idx * 2 + 1] = fcf(s1 + nob[1]);
        } else if (idx < 544) {
            const int c = idx - 512;
            const int b = c >> 1, l = c & 1;
            float s = 0.f;
            for (int q = 0; q < 16; ++q) s += cacc[(b * 16 + q) * 2 + l];
            out[b * 2 + l] = fcf(s + clsob[l]);
        }
        return;
    }

    // edge blocks
    const int b = blk >> 8;
    const int w = tid >> 6, lane = tid & 63;
    const int e = (blk & 255) * 4 + w;
    const int ps = po_ps(po);
    const int n = count_n(po, b, ps);
    const int m = n + 1;
    const size_t o = 32 + 1024 + (size_t)(b * 1024 + e) * 2;

    if (e >= m * m) {                                   // invalid: precomputed constant
        if (lane == 0) {
            out[o + 0] = fcf(econ[0] + eob[0]);
            out[o + 1] = fcf(econ[1] + eob[1]);
        }
        return;
    }

    int i = e / m, j = e - i * m;
    i = iclamp(i, 0, 31); j = iclamp(j, 0, 31);
    const ushort* urow = (const ushort*)U + (size_t)(b * 32 + j) * 1024;
    const ushort* vrow = (const ushort*)V + (size_t)(b * 32 + i) * 1024;

    float a0 = 0.f, a1 = 0.f;
    #pragma unroll
    for (int c = 0; c < 16; ++c) {
        const int idx = c * 64 + lane;
        float p = edb[idx] + us2f(urow[idx]) + us2f(vrow[idx]);
        float t = tanhf(p);
        float2 ow = ((const float2*)eoW)[idx];
        a0 = fmaf(t, ow.x, a0);
        a1 = fmaf(t, ow.y, a1);
    }
    #pragma unroll
    for (int off = 32; off > 0; off >>= 1) {
        a0 += __shfl_down(a0, off, 64);
        a1 += __shfl_down(a1, off, 64);
    }
    if (lane == 0) {
        out[o + 0] = fcf(a0 + eob[0]);
        out[o + 1] = fcf(a1 + eob[1]);
    }
}

extern "C" void kernel_launch(void* const* d_in, const int* in_sizes, int n_in,
                              void* d_out, int out_size, void* d_ws, size_t ws_size,
                              hipStream_t stream) {
    (void)out_size;
    float* out = (float*)d_out;

    bool ok = (n_in >= 16)
        && in_sizes[0] == 8388608 && in_sizes[1] == 512
        && in_sizes[2] == 1048576 && in_sizes[3] == 1024
        && in_sizes[4] == 1048576 && in_sizes[5] == 1024
        && in_sizes[6] == 2048    && in_sizes[7] == 2
        && in_sizes[8] == 1048576 && in_sizes[9] == 1024
        && in_sizes[10] == 2048   && in_sizes[11] == 2
        && in_sizes[12] == 3145728 && in_sizes[13] == 1024
        && in_sizes[14] == 2048   && in_sizes[15] == 2;
    if (!ok) {
        hipLaunchKernelGGL(k_sentinel, dim3(133), dim3(256), 0, stream, out, 33824, 111.0f);
        return;
    }

    const float* seq   = (const float*)d_in[0];
    const int*   po    = (const int*)d_in[1];
    const float* nafW  = (const float*)d_in[2];
    const float* nafb  = (const float*)d_in[3];
    const float* clsW  = (const float*)d_in[4];
    const float* clsb  = (const float*)d_in[5];
    const float* clsoW = (const float*)d_in[6];
    const float* clsob = (const float*)d_in[7];
    const float* ndW   = (const float*)d_in[8];
    const float* ndb   = (const float*)d_in[9];
    const float* noW   = (const float*)d_in[10];
    const float* nob   = (const float*)d_in[11];
    const float* eW    = (const float*)d_in[12];
    const float* edb   = (const float*)d_in[13];
    const float* eoW   = (const float*)d_in[14];
    const float* eob   = (const float*)d_in[15];

    char* ws = (char*)d_ws;

    const size_t fnB   = (size_t)512 * 1024 * 2;                // 1 MB per bf16 buffer
    const size_t naccB = (size_t)512 * 8 * 2 * sizeof(float);   // 32 KB partials
    const size_t caccB = (size_t)16 * 16 * 2 * sizeof(float);   // 2 KB partials
    const size_t econB = 64;                                    // 2 floats, padded
    const size_t wctB  = (size_t)3 * 1024 * 1024 * 2;           // 6 MB bf16 Wct
    const size_t needA = 3 * fnB + naccB + caccB + econB + wctB;
    const size_t needB = 3 * fnB + naccB + caccB;
    const size_t fnC   = (size_t)32 * 1024 * 2;
    const size_t needC = 3 * fnC + (size_t)32 * 8 * 2 * sizeof(float) + (size_t)16 * 2 * sizeof(float);

    if (ws_size >= needA) {
        bf16*   fn   = (bf16*)(ws);
        bf16*   U    = (bf16*)(ws + fnB);
        bf16*   V    = (bf16*)(ws + 2 * fnB);
        float*  nacc = (float*)(ws + 3 * fnB);
        float*  cacc = (float*)(ws + 3 * fnB + naccB);
        float*  econ = (float*)(ws + 3 * fnB + naccB + caccB);
        ushort* Wct  = (ushort*)(ws + 3 * fnB + naccB + caccB + econB);
        hipLaunchKernelGGL(k_fusedA, dim3(3841), dim3(256), 0, stream,
                           seq, po, nafW, nafb, clsW, clsb, clsoW, ndW, eW, edb, eoW,
                           fn, cacc, Wct, econ);
        hipLaunchKernelGGL(k_huv_mfma, dim3(32, 8, 3), dim3(256), 0, stream,
                           fn, Wct, ndb, noW, nacc, U, V);
        hipLaunchKernelGGL(k_fusedC, dim3(4099), dim3(256), 0, stream,
                           U, V, nacc, cacc, nob, clsob, edb, eoW, eob, econ, po, out);
    } else if (ws_size >= needB) {
        bf16*  fn   = (bf16*)(ws);
        bf16*  U    = (bf16*)(ws + fnB);
        bf16*  V    = (bf16*)(ws + 2 * fnB);
        float* nacc = (float*)(ws + 3 * fnB);
        float* cacc = (float*)(ws + 3 * fnB + naccB);
        hipLaunchKernelGGL(k_nodes, dim3(512), dim3(256), 0, stream, seq, po, fn, 0);
        hipLaunchKernelGGL(k_cls, dim3(16, 16), dim3(256), 0, stream,
                           seq, po, nafW, nafb, clsW, clsb, clsoW, fn, cacc, 0);
        hipLaunchKernelGGL(k_huv_valu, dim3(32, 8, 3), dim3(256), 0, stream,
                           fn, ndW, ndb, noW, eW, nacc, U, V);
        hipLaunchKernelGGL(k_fin2, dim3(3), dim3(256), 0, stream, nacc, cacc, nob, clsob, out, 0, 16);
        hipLaunchKernelGGL(k_edge, dim3(4096), dim3(256), 0, stream,
                           U, V, edb, eoW, eob, po, out, 0);
    } else if (ws_size >= needC) {
        bf16*  fn   = (bf16*)(ws);
        bf16*  U    = (bf16*)(ws + fnC);
        bf16*  V    = (bf16*)(ws + 2 * fnC);
        float* nacc = (float*)(ws + 3 * fnC);
        float* cacc = nacc + 32 * 8 * 2;
        for (int b = 0; b < 16; ++b) {
            hipLaunchKernelGGL(k_nodes, dim3(32), dim3(256), 0, stream, seq, po, fn, b);
            hipLaunchKernelGGL(k_cls, dim3(1, 16), dim3(256), 0, stream,
                               seq, po, nafW, nafb, clsW, clsb, clsoW, fn, cacc, b);
            hipLaunchKernelGGL(k_huv_valu, dim3(2, 8, 3), dim3(256), 0, stream,
                               fn, ndW, ndb, noW, eW, nacc, U, V);
            hipLaunchKernelGGL(k_fin2, dim3(1), dim3(256), 0, stream, nacc, cacc, nob, clsob, out, b, 1);
            hipLaunchKernelGGL(k_edge, dim3(256), dim3(256), 0, stream,
                               U, V, edb, eoW, eob, po, out, b);
        }
    } else {
        hipLaunchKernelGGL(k_sentinel, dim3(133), dim3(256), 0, stream, out, 33824, 222.0f);
    }
}